// Round 18
// baseline (74.742 us; speedup 1.0000x reference)
//
#include <hip/hip_runtime.h>
#include <hip/hip_fp16.h>
#include <math.h>

#define BATCH 131072
#define NSTEPS 256
#define LGN 7
#define NPTS 128           // (1 << LGN)
#define ZSPAN 12.0f        // z in [-6, 6]
#define ZLO 6.0f
#define ZSCALE (NPTS / ZSPAN)      // entries per sigma (10.667)
#define DZ (ZSPAN / NPTS)          // 0.09375
#define MU_C 0.72134752044448170367f   // (mu - sigma^2/2)/ln2 = 0.5/ln2
#define SD_C 1.4426950408889634f       // sigma/ln2
#define LSTRIDE 132        // padded LDS row stride (entries)

using f32x2 = __attribute__((ext_vector_type(2))) float;

__device__ __forceinline__ float fast_exp(float x) {
    return __builtin_amdgcn_exp2f(x * 1.44269504088896340736f);
}
__device__ __forceinline__ float fast_rcp(float x) {
    return __builtin_amdgcn_rcpf(x);
}
__device__ __forceinline__ float sigmoidf_fast(float x) {
    return fast_rcp(1.0f + fast_exp(-x));
}

#define REP32(M) M(0) M(1) M(2) M(3) M(4) M(5) M(6) M(7) \
                 M(8) M(9) M(10) M(11) M(12) M(13) M(14) M(15) \
                 M(16) M(17) M(18) M(19) M(20) M(21) M(22) M(23) \
                 M(24) M(25) M(26) M(27) M(28) M(29) M(30) M(31)

#define REP16(M) M(0) M(1) M(2) M(3) M(4) M(5) M(6) M(7) \
                 M(8) M(9) M(10) M(11) M(12) M(13) M(14) M(15)

#define REP8(M) M(0) M(1) M(2) M(3) M(4) M(5) M(6) M(7)

// Shared MLP+tangent body (see R4). Produces h and pre-sigmoid tangent acc.
#define MLP_BODY(W1r, B1, W2r, B2, W3r, b3v, t, s, sd, H, HACC) \
    { \
        const float __t = (t), __s = (s), __sd = (sd); \
        f32x2 acc2 = {(b3v), 0.0f}; \
        REP32(MLP_L1) \
        REP32(MLP_ROW) \
        H = sigmoidf_fast(acc2.x); \
        HACC = acc2.y; \
    }

#define MLP_L1(j) f32x2 at##j; { \
    const float2 wv = W1r[j]; \
    const float z  = fmaf(wv.x, __t, fmaf(wv.y, __s, B1[j])); \
    const float zd = wv.y * __sd; \
    const float sg = sigmoidf_fast(z); \
    const float da = sg * (1.0f + z * (1.0f - sg)); \
    at##j = (f32x2){z * sg, da * zd}; }

#define MLP_ROW(j) { \
    const float4 q0 = W2r[(j) * 8 + 0]; \
    const float4 q1 = W2r[(j) * 8 + 1]; \
    const float4 q2 = W2r[(j) * 8 + 2]; \
    const float4 q3 = W2r[(j) * 8 + 3]; \
    const float4 q4 = W2r[(j) * 8 + 4]; \
    const float4 q5 = W2r[(j) * 8 + 5]; \
    const float4 q6 = W2r[(j) * 8 + 6]; \
    const float4 q7 = W2r[(j) * 8 + 7]; \
    f32x2 zza = {B2[j], 0.0f}; \
    f32x2 zzb = {0.0f, 0.0f}; \
    zza += (f32x2){q0.x, q0.x} * at0;  zzb += (f32x2){q0.y, q0.y} * at1; \
    zza += (f32x2){q0.z, q0.z} * at2;  zzb += (f32x2){q0.w, q0.w} * at3; \
    zza += (f32x2){q1.x, q1.x} * at4;  zzb += (f32x2){q1.y, q1.y} * at5; \
    zza += (f32x2){q1.z, q1.z} * at6;  zzb += (f32x2){q1.w, q1.w} * at7; \
    zza += (f32x2){q2.x, q2.x} * at8;  zzb += (f32x2){q2.y, q2.y} * at9; \
    zza += (f32x2){q2.z, q2.z} * at10; zzb += (f32x2){q2.w, q2.w} * at11; \
    zza += (f32x2){q3.x, q3.x} * at12; zzb += (f32x2){q3.y, q3.y} * at13; \
    zza += (f32x2){q3.z, q3.z} * at14; zzb += (f32x2){q3.w, q3.w} * at15; \
    zza += (f32x2){q4.x, q4.x} * at16; zzb += (f32x2){q4.y, q4.y} * at17; \
    zza += (f32x2){q4.z, q4.z} * at18; zzb += (f32x2){q4.w, q4.w} * at19; \
    zza += (f32x2){q5.x, q5.x} * at20; zzb += (f32x2){q5.y, q5.y} * at21; \
    zza += (f32x2){q5.z, q5.z} * at22; zzb += (f32x2){q5.w, q5.w} * at23; \
    zza += (f32x2){q6.x, q6.x} * at24; zzb += (f32x2){q6.y, q6.y} * at25; \
    zza += (f32x2){q6.z, q6.z} * at26; zzb += (f32x2){q6.w, q6.w} * at27; \
    zza += (f32x2){q7.x, q7.x} * at28; zzb += (f32x2){q7.y, q7.y} * at29; \
    zza += (f32x2){q7.z, q7.z} * at30; zzb += (f32x2){q7.w, q7.w} * at31; \
    const f32x2 zzt = zza + zzb; \
    const float zv  = zzt.x; \
    const float sg  = sigmoidf_fast(zv); \
    const float da  = sg * (1.0f + zv * (1.0f - sg)); \
    const float w3  = W3r[j]; \
    acc2 += (f32x2){w3, w3} * (f32x2){zv * sg, da * zzt.y}; \
}

// ---------------------------------------------------------------------------
// Kernel 1: evaluate packed half2{h, q} at standardized grid points, written
// directly into the paired table (T2[st][k].x and T2[st][k-1].y).
// ---------------------------------------------------------------------------
__global__ __launch_bounds__(256) void table_eval_kernel(
    const float* __restrict__ ts,
    const float* __restrict__ W1, const float* __restrict__ b1,
    const float* __restrict__ W2, const float* __restrict__ b2,
    const float* __restrict__ W3, const float* __restrict__ b3,
    unsigned int* __restrict__ W)      // = (unsigned int*)T2, 2 words/entry
{
    __shared__ __align__(16) float sW1[64];
    __shared__ float sb1[32];
    __shared__ __align__(16) float sW2[1024];
    __shared__ float sb2[32];
    __shared__ float sW3[32];
    __shared__ float sb3[1];

    const int tid = threadIdx.x;
    for (int i = tid; i < 1024; i += 256) sW2[i] = W2[i];
    if (tid < 64) sW1[tid] = W1[tid];
    if (tid < 32) { sb1[tid] = b1[tid]; sb2[tid] = b2[tid]; sW3[tid] = W3[tid]; }
    if (tid == 0) sb3[0] = b3[0];
    __syncthreads();

    const float2* W1r = (const float2*)sW1;
    const float*  B1  = sb1;
    const float4* W2r = (const float4*)sW2;
    const float*  B2  = sb2;
    const float*  W3r = sW3;
    const float   b3v = sb3[0];

    const int gid = blockIdx.x * 256 + tid;
    const int st = gid >> LGN;
    const int k  = gid & (NPTS - 1);

    const float t  = ts[st];
    const float mu = MU_C * t;
    const float sd = SD_C * __builtin_sqrtf(t) + 1e-4f;
    const float zz = fmaf((float)k, DZ, -ZLO);
    const float s  = __builtin_amdgcn_exp2f(fmaf(zz, sd, mu));

    float h, hacc;
    MLP_BODY(W1r, B1, W2r, B2, W3r, b3v, t, s, 1.0f, h, hacc)

    const float q = h * (1.0f - h) * hacc * s;   // s * dh/ds (Hermite tangent)
    __half2 p = __floats2half2_rn(h, q);
    const unsigned int pv = *(unsigned int*)&p;

    W[2 * gid] = pv;                       // T2[st][k].x
    if (k > 0)         W[2 * gid - 1] = pv;  // T2[st][k-1].y
    if (k == NPTS - 1) W[2 * gid + 1] = pv;  // row-end clamp
}

// ---------------------------------------------------------------------------
// Kernel 2: SDE path integration with LDS-staged table rows.
// Per 32-step body: issue 8 uint4 global loads of the NEXT body's 32 table
// rows (32 KB), compute current body entirely from LDS (ds_read_b64 gathers),
// prefetch noise depth-2, then ds_write the staged rows into the other
// buffer and one __syncthreads. Gathers never touch L2 in the hot loop --
// R17 showed the residual was L2 round-trips, not load scheduling (doubling
// in-flight gathers changed nothing; three pin variants changed nothing).
// ---------------------------------------------------------------------------
__global__ __launch_bounds__(256, 2) void path_kernel(
    const float* __restrict__ noise,   // (NSTEPS, BATCH)
    const float* __restrict__ ts,      // (NSTEPS+1)
    const float* __restrict__ wq,      // scalar
    const uint2* __restrict__ T2,      // (NSTEPS, NPTS) paired entries
    float* __restrict__ out)           // (BATCH)
{
    __shared__ float4 sdt4[NSTEPS];    // {dt, sqrt(dt), c', w'}: u = x*w' + c'
    __shared__ float  scr[NSTEPS];     // cr = ln2 / w' (Hermite tangent scale)
    __shared__ __align__(16) uint2 Lw[2][32 * LSTRIDE];   // 67.6 KB

    const int tid = threadIdx.x;
    if (tid < NSTEPS) {
        const float t0  = ts[tid];
        const float dtv = ts[tid + 1] - t0;
        const float sdv = SD_C * __builtin_sqrtf(t0) + 1e-4f;
        const float wp  = fast_rcp(sdv) * ZSCALE;
        const float cp  = ZLO * ZSCALE - MU_C * t0 * wp;
        sdt4[tid] = make_float4(dtv, __builtin_sqrtf(dtv), cp, wp);
        scr[tid]  = 0.69314718056f * fast_rcp(wp);
    }

    // pre-stage body 0 (rows 0..31) into Lw[0]
    #pragma unroll
    for (int j = 0; j < 8; ++j) {
        const uint4 v = ((const uint4*)T2)[j * 256 + tid];
        const int fl = (j * 256 + tid) * 2;
        const int r = fl >> 7, i = fl & 127;
        *(uint4*)&Lw[0][r * LSTRIDE + i] = v;
    }
    __syncthreads();

    const int gid = blockIdx.x * 256 + tid;
    const float* np_ = noise + gid;
    const float umax = (float)NPTS - 1.001f;

    float s   = 1.0f;
    float pnl = 0.0f;

    // preload noise for steps 0-15 (set A) and 16-31 (set B)
    #define NL0(k) float nA##k = np_[(size_t)(k) * BATCH]; \
                   float nB##k = np_[(size_t)(16 + k) * BATCH];
    REP16(NL0)
    #undef NL0

    // next-body table load / store (8 named uint4 regs; rule #20)
    #define GLD(j) const uint4 G##j = srcN[(j) * 256 + tid];
    #define GST(j) { const int fl = ((j) * 256 + tid) * 2; \
                     const int r = fl >> 7, i = fl & 127; \
                     *(uint4*)&Lw[nxt][r * LSTRIDE + i] = G##j; }

    // per-step: s-chain + LDS gather + P/Q precompute
    #define CHK(k, G, NPv, BASE, R0) \
        const float4 dq##G##k = sdt4[(BASE) + k]; \
        const float dW##G##k  = NPv##k * dq##G##k.y; \
        const float mil##G##k = 0.5f * fmaf(dW##G##k, dW##G##k, -dq##G##k.x); \
        const float Af##G##k  = dq##G##k.x + dW##G##k + mil##G##k; \
        const float sv##G##k  = s; \
        s = fmaf(s, Af##G##k, s); \
        const float P##G##k = sv##G##k * Af##G##k; \
        const float Q##G##k = sv##G##k * mil##G##k; \
        const float x##G##k = __builtin_amdgcn_logf(sv##G##k); \
        const float u##G##k = \
            fminf(fmaxf(fmaf(x##G##k, dq##G##k.w, dq##G##k.z), 0.0f), umax); \
        const int   i0##G##k = (int)u##G##k; \
        const float f##G##k  = u##G##k - (float)i0##G##k; \
        const uint2 E##G##k = Lrd[((R0) + k) * LSTRIDE + i0##G##k];

    // noise prefetch (rows PFB..PFB+15 into set NPv; consumed next body)
    #define NPF(k, NPv, PFB) NPv##k = np_[(size_t)((PFB) + k) * BATCH];

    // consume: cubic Hermite for h, linear for q; pnl += hh*P + qq*Q
    #define PNK(k, G, BASE) { \
        const float2 a0 = __half22float2(*(const __half2*)&E##G##k.x); \
        const float2 a1 = __half22float2(*(const __half2*)&E##G##k.y); \
        const float cr = scr[(BASE) + k]; \
        const float uu = f##G##k; \
        const float m  = uu * uu; \
        const float n  = m * uu; \
        const float dh = a1.x - a0.x; \
        const float ba = fmaf(-2.0f, n, 3.0f * m);            /* 3u^2-2u^3 */ \
        const float bb = fmaf(-2.0f, m, uu) + n;              /* u^3-2u^2+u */ \
        const float bc = n - m;                               /* u^3-u^2 */ \
        const float hh = fmaf(dh, ba, a0.x) + cr * fmaf(a0.y, bb, a1.y * bc); \
        const float qq = fmaf(uu, a1.y - a0.y, a0.y); \
        pnl = fmaf(hh, P##G##k, fmaf(qq, Q##G##k, pnl)); }

    #define CHA(k) CHK(k, A, nA, baseA, 0)
    #define CHB(k) CHK(k, B, nB, baseB, 16)
    #define NPA(k) NPF(k, nA, pfA)
    #define NPB(k) NPF(k, nB, pfB)
    #define PNA(k) PNK(k, A, baseA)
    #define PNB(k) PNK(k, B, baseB)

    #pragma unroll 1
    for (int cc = 0; cc < NSTEPS / 32; ++cc) {
        const int cur = cc & 1, nxt = cur ^ 1;
        const int baseA = cc * 32;
        const int baseB = baseA + 16;
        const int nb = min(cc + 1, NSTEPS / 32 - 1);
        const uint4* srcN = (const uint4*)(T2 + (size_t)nb * 32 * NPTS);
        const uint2* Lrd = Lw[cur];
        const int pfA = min(baseA + 32, NSTEPS - 32);
        const int pfB = pfA + 16;

        REP8(GLD)          // issue next-body table loads (in flight all body)
        REP16(CHA)         // s-chain + LDS gathers, steps 0-15
        REP16(CHB)         // steps 16-31
        REP16(NPA)         // noise prefetch, depth ~1 body
        REP16(NPB)
        REP16(PNA)         // consume
        REP16(PNB)
        REP8(GST)          // write staged rows (waits on G loads)
        __syncthreads();
    }

    #undef CHA
    #undef CHB
    #undef NPA
    #undef NPB
    #undef PNA
    #undef PNB
    #undef PNK
    #undef NPF
    #undef CHK
    #undef GLD
    #undef GST

    const float z = fmaxf(0.0f, s - 3.0f);
    const float d = z - pnl - wq[0];
    out[gid] = d * d;
}

// ---------------------------------------------------------------------------
// Fallback: direct per-thread MLP evaluation (R4 kernel) if ws too small.
// ---------------------------------------------------------------------------
__global__ __launch_bounds__(256, 3) void deep_hedging_direct(
    const float* __restrict__ noise, const float* __restrict__ ts,
    const float* __restrict__ w,
    const float* __restrict__ W1, const float* __restrict__ b1,
    const float* __restrict__ W2, const float* __restrict__ b2,
    const float* __restrict__ W3, const float* __restrict__ b3,
    float* __restrict__ out)
{
    __shared__ __align__(16) float sW1[64];
    __shared__ float sb1[32];
    __shared__ __align__(16) float sW2[1024];
    __shared__ float sb2[32];
    __shared__ float sW3[32];
    __shared__ float sb3w[2];
    __shared__ float sts[NSTEPS + 1];

    const int tid = threadIdx.x;
    for (int i = tid; i < 1024; i += 256) sW2[i] = W2[i];
    if (tid < 64) sW1[tid] = W1[tid];
    if (tid < 32) { sb1[tid] = b1[tid]; sb2[tid] = b2[tid]; sW3[tid] = W3[tid]; }
    if (tid == 0) { sb3w[0] = b3[0]; sb3w[1] = w[0]; }
    for (int i = tid; i < NSTEPS + 1; i += 256) sts[i] = ts[i];
    __syncthreads();

    const int gid = blockIdx.x * 256 + tid;
    const float* np_ = noise + gid;

    float s   = 1.0f;
    float pnl = 0.0f;
    const float b3v = sb3w[0];
    const float wv_ = sb3w[1];

    #pragma unroll 1
    for (int st = 0; st < NSTEPS; ++st) {
        int zr = 0;
        asm volatile("" : "+v"(zr));   // block LICM of weight loads
        const float2* W1r = (const float2*)sW1 + zr;
        const float*  B1  = sb1 + zr;
        const float4* W2r = (const float4*)sW2 + zr;
        const float*  B2  = sb2 + zr;
        const float*  W3r = sW3 + zr;

        const float t  = sts[st];
        const float dt = sts[st + 1] - t;
        const float dW = np_[(size_t)st * BATCH] * __builtin_sqrtf(dt);
        const float sd = s;

        float h, hacc;
        MLP_BODY(W1r, B1, W2r, B2, W3r, b3v, t, s, sd, h, hacc)
        const float hd = h * (1.0f - h) * hacc;

        const float mil = 0.5f * (dW * dW - dt);
        const float g1  = s * h;
        const float dg1 = fmaf(sd, h, s * hd);
        const float snew = s + s * dt + s * dW + sd * mil;
        pnl = pnl + g1 * dt + g1 * dW + dg1 * mil;
        s = snew;
    }

    const float z = fmaxf(0.0f, s - 3.0f);
    const float d = z - pnl - wv_;
    out[gid] = d * d;
}

extern "C" void kernel_launch(void* const* d_in, const int* in_sizes, int n_in,
                              void* d_out, int out_size, void* d_ws, size_t ws_size,
                              hipStream_t stream) {
    const float* noise = (const float*)d_in[0];
    const float* ts    = (const float*)d_in[1];
    const float* w     = (const float*)d_in[2];
    const float* W1    = (const float*)d_in[3];
    const float* b1    = (const float*)d_in[4];
    const float* W2    = (const float*)d_in[5];
    const float* b2    = (const float*)d_in[6];
    const float* W3    = (const float*)d_in[7];
    const float* b3    = (const float*)d_in[8];
    float* out = (float*)d_out;

    const size_t nA   = (size_t)NSTEPS * NPTS;           // entries
    const size_t need = nA * sizeof(uint2);              // 256 KB

    if (ws_size >= need) {
        uint2* T2 = (uint2*)d_ws;

        dim3 tb(256), tg(nA / 256);
        table_eval_kernel<<<tg, tb, 0, stream>>>(ts, W1, b1, W2, b2, W3, b3,
                                                 (unsigned int*)T2);
        dim3 pb(256), pg(BATCH / 256);
        path_kernel<<<pg, pb, 0, stream>>>(noise, ts, w, T2, out);
    } else {
        dim3 grid(BATCH / 256), block(256);
        deep_hedging_direct<<<grid, block, 0, stream>>>(noise, ts, w, W1, b1,
                                                        W2, b2, W3, b3, out);
    }
}

// Round 19
// 72.639 us; speedup vs baseline: 1.0290x; 1.0290x over previous
//
#include <hip/hip_runtime.h>
#include <hip/hip_fp16.h>
#include <math.h>

#define BATCH 131072
#define NSTEPS 256
#define SEGLEN 64
#define NSEG 4
#define LGN 7
#define NPTS 128           // (1 << LGN)
#define ZSPAN 12.0f        // z in [-6, 6]
#define ZLO 6.0f
#define ZSCALE (NPTS / ZSPAN)      // entries per sigma (10.667)
#define DZ (ZSPAN / NPTS)          // 0.09375
#define MU_C 0.72134752044448170367f   // (mu - sigma^2/2)/ln2 = 0.5/ln2
#define SD_C 1.4426950408889634f       // sigma/ln2

using f32x2 = __attribute__((ext_vector_type(2))) float;

__device__ __forceinline__ float fast_exp(float x) {
    return __builtin_amdgcn_exp2f(x * 1.44269504088896340736f);
}
__device__ __forceinline__ float fast_rcp(float x) {
    return __builtin_amdgcn_rcpf(x);
}
__device__ __forceinline__ float sigmoidf_fast(float x) {
    return fast_rcp(1.0f + fast_exp(-x));
}

#define REP32(M) M(0) M(1) M(2) M(3) M(4) M(5) M(6) M(7) \
                 M(8) M(9) M(10) M(11) M(12) M(13) M(14) M(15) \
                 M(16) M(17) M(18) M(19) M(20) M(21) M(22) M(23) \
                 M(24) M(25) M(26) M(27) M(28) M(29) M(30) M(31)

#define REP8(M) M(0) M(1) M(2) M(3) M(4) M(5) M(6) M(7)

// Shared MLP+tangent body (see R4). Produces h and pre-sigmoid tangent acc.
#define MLP_BODY(W1r, B1, W2r, B2, W3r, b3v, t, s, sd, H, HACC) \
    { \
        const float __t = (t), __s = (s), __sd = (sd); \
        f32x2 acc2 = {(b3v), 0.0f}; \
        REP32(MLP_L1) \
        REP32(MLP_ROW) \
        H = sigmoidf_fast(acc2.x); \
        HACC = acc2.y; \
    }

#define MLP_L1(j) f32x2 at##j; { \
    const float2 wv = W1r[j]; \
    const float z  = fmaf(wv.x, __t, fmaf(wv.y, __s, B1[j])); \
    const float zd = wv.y * __sd; \
    const float sg = sigmoidf_fast(z); \
    const float da = sg * (1.0f + z * (1.0f - sg)); \
    at##j = (f32x2){z * sg, da * zd}; }

#define MLP_ROW(j) { \
    const float4 q0 = W2r[(j) * 8 + 0]; \
    const float4 q1 = W2r[(j) * 8 + 1]; \
    const float4 q2 = W2r[(j) * 8 + 2]; \
    const float4 q3 = W2r[(j) * 8 + 3]; \
    const float4 q4 = W2r[(j) * 8 + 4]; \
    const float4 q5 = W2r[(j) * 8 + 5]; \
    const float4 q6 = W2r[(j) * 8 + 6]; \
    const float4 q7 = W2r[(j) * 8 + 7]; \
    f32x2 zza = {B2[j], 0.0f}; \
    f32x2 zzb = {0.0f, 0.0f}; \
    zza += (f32x2){q0.x, q0.x} * at0;  zzb += (f32x2){q0.y, q0.y} * at1; \
    zza += (f32x2){q0.z, q0.z} * at2;  zzb += (f32x2){q0.w, q0.w} * at3; \
    zza += (f32x2){q1.x, q1.x} * at4;  zzb += (f32x2){q1.y, q1.y} * at5; \
    zza += (f32x2){q1.z, q1.z} * at6;  zzb += (f32x2){q1.w, q1.w} * at7; \
    zza += (f32x2){q2.x, q2.x} * at8;  zzb += (f32x2){q2.y, q2.y} * at9; \
    zza += (f32x2){q2.z, q2.z} * at10; zzb += (f32x2){q2.w, q2.w} * at11; \
    zza += (f32x2){q3.x, q3.x} * at12; zzb += (f32x2){q3.y, q3.y} * at13; \
    zza += (f32x2){q3.z, q3.z} * at14; zzb += (f32x2){q3.w, q3.w} * at15; \
    zza += (f32x2){q4.x, q4.x} * at16; zzb += (f32x2){q4.y, q4.y} * at17; \
    zza += (f32x2){q4.z, q4.z} * at18; zzb += (f32x2){q4.w, q4.w} * at19; \
    zza += (f32x2){q5.x, q5.x} * at20; zzb += (f32x2){q5.y, q5.y} * at21; \
    zza += (f32x2){q5.z, q5.z} * at22; zzb += (f32x2){q5.w, q5.w} * at23; \
    zza += (f32x2){q6.x, q6.x} * at24; zzb += (f32x2){q6.y, q6.y} * at25; \
    zza += (f32x2){q6.z, q6.z} * at26; zzb += (f32x2){q6.w, q6.w} * at27; \
    zza += (f32x2){q7.x, q7.x} * at28; zzb += (f32x2){q7.y, q7.y} * at29; \
    zza += (f32x2){q7.z, q7.z} * at30; zzb += (f32x2){q7.w, q7.w} * at31; \
    const f32x2 zzt = zza + zzb; \
    const float zv  = zzt.x; \
    const float sg  = sigmoidf_fast(zv); \
    const float da  = sg * (1.0f + zv * (1.0f - sg)); \
    const float w3  = W3r[j]; \
    acc2 += (f32x2){w3, w3} * (f32x2){zv * sg, da * zzt.y}; \
}

// ---------------------------------------------------------------------------
// Kernel 1: table of packed half2{h, q} at standardized grid points, paired.
// ---------------------------------------------------------------------------
__global__ __launch_bounds__(256) void table_eval_kernel(
    const float* __restrict__ ts,
    const float* __restrict__ W1, const float* __restrict__ b1,
    const float* __restrict__ W2, const float* __restrict__ b2,
    const float* __restrict__ W3, const float* __restrict__ b3,
    unsigned int* __restrict__ W)      // = (unsigned int*)T2, 2 words/entry
{
    __shared__ __align__(16) float sW1[64];
    __shared__ float sb1[32];
    __shared__ __align__(16) float sW2[1024];
    __shared__ float sb2[32];
    __shared__ float sW3[32];
    __shared__ float sb3[1];

    const int tid = threadIdx.x;
    for (int i = tid; i < 1024; i += 256) sW2[i] = W2[i];
    if (tid < 64) sW1[tid] = W1[tid];
    if (tid < 32) { sb1[tid] = b1[tid]; sb2[tid] = b2[tid]; sW3[tid] = W3[tid]; }
    if (tid == 0) sb3[0] = b3[0];
    __syncthreads();

    const float2* W1r = (const float2*)sW1;
    const float*  B1  = sb1;
    const float4* W2r = (const float4*)sW2;
    const float*  B2  = sb2;
    const float*  W3r = sW3;
    const float   b3v = sb3[0];

    const int gid = blockIdx.x * 256 + tid;
    const int st = gid >> LGN;
    const int k  = gid & (NPTS - 1);

    const float t  = ts[st];
    const float mu = MU_C * t;
    const float sd = SD_C * __builtin_sqrtf(t) + 1e-4f;
    const float zz = fmaf((float)k, DZ, -ZLO);
    const float s  = __builtin_amdgcn_exp2f(fmaf(zz, sd, mu));

    float h, hacc;
    MLP_BODY(W1r, B1, W2r, B2, W3r, b3v, t, s, 1.0f, h, hacc)

    const float q = h * (1.0f - h) * hacc * s;   // s * dh/ds (Hermite tangent)
    __half2 p = __floats2half2_rn(h, q);
    const unsigned int pv = *(unsigned int*)&p;

    W[2 * gid] = pv;                       // T2[st][k].x
    if (k > 0)         W[2 * gid - 1] = pv;  // T2[st][k-1].y
    if (k == NPTS - 1) W[2 * gid + 1] = pv;  // row-end clamp
}

// ---------------------------------------------------------------------------
// Kernel 2: segment products.  A_n = dt+dW+mil depends only on noise, so
// s is a prefix PRODUCT: thread (g,path) computes P_g = prod(1+A) over
// segment g (g = 0..2; segment 3's product is never needed standalone).
// ---------------------------------------------------------------------------
__global__ __launch_bounds__(256) void prod_kernel(
    const float* __restrict__ noise,   // (NSTEPS, BATCH)
    const float* __restrict__ ts,
    float* __restrict__ P)             // (3, BATCH)
{
    __shared__ float2 sdt[SEGLEN];     // {dt, sqrt(dt)} for this segment
    const int g    = blockIdx.x >> 9;          // 512 blocks per segment
    const int pblk = blockIdx.x & 511;
    const int tid  = threadIdx.x;
    const int sbase = g * SEGLEN;

    if (tid < SEGLEN) {
        const float t0 = ts[sbase + tid];
        const float dtv = ts[sbase + tid + 1] - t0;
        sdt[tid] = make_float2(dtv, __builtin_sqrtf(dtv));
    }
    __syncthreads();

    const int path = pblk * 256 + tid;
    const float* np_ = noise + (size_t)sbase * BATCH + path;

    float prod = 1.0f;
    #pragma unroll 8
    for (int k = 0; k < SEGLEN; ++k) {
        const float2 d = sdt[k];
        const float dW  = np_[(size_t)k * BATCH] * d.y;
        const float mil = 0.5f * fmaf(dW, dW, -d.x);
        const float A   = d.x + dW + mil;
        prod = fmaf(prod, A, prod);
    }
    P[(size_t)g * BATCH + path] = prod;
}

// ---------------------------------------------------------------------------
// Kernel 3: per-segment table pass.  4*BATCH threads (4x the TLP of the
// single-kernel formulation -- R14-R18 showed the residual was latency
// exposure at 2 waves/SIMD, immune to ILP/pinning/LDS).  Segment g starts
// at s = P_0*..*P_{g-1}; 8-step chunks with next-chunk noise prefetch;
// cubic Hermite h + linear q from the paired half2 table.
// Seg 0 writes its pnl into out[] (scratch); seg 3 also writes s_T.
// ---------------------------------------------------------------------------
__global__ __launch_bounds__(256, 4) void seg_kernel(
    const float* __restrict__ noise,   // (NSTEPS, BATCH)
    const float* __restrict__ ts,
    const uint2* __restrict__ T2,      // (NSTEPS, NPTS)
    const float* __restrict__ P,       // (3, BATCH)
    float* __restrict__ pnlb,          // (3, BATCH)  segs 1-3
    float* __restrict__ sT,            // (BATCH)
    float* __restrict__ out)           // (BATCH)     seg-0 pnl scratch
{
    __shared__ float4 sdt4[SEGLEN];    // {dt, sqrt(dt), c', w'}
    __shared__ float  scr[SEGLEN];     // cr = ln2 / w'
    const int g    = blockIdx.x >> 9;
    const int pblk = blockIdx.x & 511;
    const int tid  = threadIdx.x;
    const int sbase = g * SEGLEN;

    if (tid < SEGLEN) {
        const float t0  = ts[sbase + tid];
        const float dtv = ts[sbase + tid + 1] - t0;
        const float sdv = SD_C * __builtin_sqrtf(t0) + 1e-4f;
        const float wp  = fast_rcp(sdv) * ZSCALE;
        const float cp  = ZLO * ZSCALE - MU_C * t0 * wp;
        sdt4[tid] = make_float4(dtv, __builtin_sqrtf(dtv), cp, wp);
        scr[tid]  = 0.69314718056f * fast_rcp(wp);
    }
    __syncthreads();

    const int path = pblk * 256 + tid;
    const float* np_ = noise + (size_t)sbase * BATCH + path;
    const float umax = (float)NPTS - 1.001f;

    float s = 1.0f;                    // uniform branches: g same per block
    if (g > 0) s = P[path];
    if (g > 1) s *= P[BATCH + path];
    if (g > 2) s *= P[2 * BATCH + path];
    float pnl = 0.0f;

    // preload chunk 0 noise
    #define NLD0(k) float n##k = np_[(size_t)(k) * BATCH];
    REP8(NLD0)
    #undef NLD0

    #pragma unroll 1
    for (int cc = 0; cc < SEGLEN / 8; ++cc) {
        const int coff = cc * 8;
        const int pfo  = min(coff + 8, SEGLEN - 8);
        const float* nb = np_ + (size_t)pfo * BATCH;

        // prefetch next chunk's noise
        #define NPF(k) const float m##k = nb[(size_t)(k) * BATCH];
        REP8(NPF)
        #undef NPF

        // s-chain + issue 8 paired gathers
        #define CHK(k) \
            const float4 dq##k = sdt4[coff + k]; \
            const float dW##k  = n##k * dq##k.y; \
            const float mil##k = 0.5f * fmaf(dW##k, dW##k, -dq##k.x); \
            const float Af##k  = dq##k.x + dW##k + mil##k; \
            const float sv##k  = s; \
            s = fmaf(s, Af##k, s); \
            const float Pv##k = sv##k * Af##k; \
            const float Qv##k = sv##k * mil##k; \
            const float x##k = __builtin_amdgcn_logf(sv##k); \
            const float u##k = \
                fminf(fmaxf(fmaf(x##k, dq##k.w, dq##k.z), 0.0f), umax); \
            const int   i0##k = (int)u##k; \
            const float f##k  = u##k - (float)i0##k; \
            const uint2 E##k = \
                T2[((size_t)(sbase + coff + k) << LGN) + i0##k];
        REP8(CHK)
        #undef CHK

        // consume: cubic Hermite h, linear q; pnl += hh*Pv + qq*Qv
        #define PNK(k) { \
            const float2 a0 = __half22float2(*(const __half2*)&E##k.x); \
            const float2 a1 = __half22float2(*(const __half2*)&E##k.y); \
            const float cr = scr[coff + k]; \
            const float uu = f##k; \
            const float m  = uu * uu; \
            const float n  = m * uu; \
            const float dh = a1.x - a0.x; \
            const float ba = fmaf(-2.0f, n, 3.0f * m); \
            const float bb = fmaf(-2.0f, m, uu) + n; \
            const float bc = n - m; \
            const float hh = fmaf(dh, ba, a0.x) + cr * fmaf(a0.y, bb, a1.y * bc); \
            const float qq = fmaf(uu, a1.y - a0.y, a0.y); \
            pnl = fmaf(hh, Pv##k, fmaf(qq, Qv##k, pnl)); }
        REP8(PNK)
        #undef PNK

        // rotate prefetched noise
        #define NRT(k) n##k = m##k;
        REP8(NRT)
        #undef NRT
    }

    if (g == 0) {
        out[path] = pnl;               // scratch; fin_kernel combines
    } else {
        pnlb[(size_t)(g - 1) * BATCH + path] = pnl;
    }
    if (g == 3) sT[path] = s;
}

// ---------------------------------------------------------------------------
// Kernel 4: combine.
// ---------------------------------------------------------------------------
__global__ __launch_bounds__(256) void fin_kernel(
    const float* __restrict__ pnlb, const float* __restrict__ sT,
    const float* __restrict__ wq, float* __restrict__ out)
{
    const int p = blockIdx.x * 256 + threadIdx.x;
    const float pnl = out[p] + pnlb[p] + pnlb[BATCH + p] + pnlb[2 * BATCH + p];
    const float z = fmaxf(0.0f, sT[p] - 3.0f);
    const float d = z - pnl - wq[0];
    out[p] = d * d;
}

// ---------------------------------------------------------------------------
// Fallback: direct per-thread MLP evaluation (R4 kernel) if ws too small.
// ---------------------------------------------------------------------------
__global__ __launch_bounds__(256, 3) void deep_hedging_direct(
    const float* __restrict__ noise, const float* __restrict__ ts,
    const float* __restrict__ w,
    const float* __restrict__ W1, const float* __restrict__ b1,
    const float* __restrict__ W2, const float* __restrict__ b2,
    const float* __restrict__ W3, const float* __restrict__ b3,
    float* __restrict__ out)
{
    __shared__ __align__(16) float sW1[64];
    __shared__ float sb1[32];
    __shared__ __align__(16) float sW2[1024];
    __shared__ float sb2[32];
    __shared__ float sW3[32];
    __shared__ float sb3w[2];
    __shared__ float sts[NSTEPS + 1];

    const int tid = threadIdx.x;
    for (int i = tid; i < 1024; i += 256) sW2[i] = W2[i];
    if (tid < 64) sW1[tid] = W1[tid];
    if (tid < 32) { sb1[tid] = b1[tid]; sb2[tid] = b2[tid]; sW3[tid] = W3[tid]; }
    if (tid == 0) { sb3w[0] = b3[0]; sb3w[1] = w[0]; }
    for (int i = tid; i < NSTEPS + 1; i += 256) sts[i] = ts[i];
    __syncthreads();

    const int gid = blockIdx.x * 256 + tid;
    const float* np_ = noise + gid;

    float s   = 1.0f;
    float pnl = 0.0f;
    const float b3v = sb3w[0];
    const float wv_ = sb3w[1];

    #pragma unroll 1
    for (int st = 0; st < NSTEPS; ++st) {
        int zr = 0;
        asm volatile("" : "+v"(zr));   // block LICM of weight loads
        const float2* W1r = (const float2*)sW1 + zr;
        const float*  B1  = sb1 + zr;
        const float4* W2r = (const float4*)sW2 + zr;
        const float*  B2  = sb2 + zr;
        const float*  W3r = sW3 + zr;

        const float t  = sts[st];
        const float dt = sts[st + 1] - t;
        const float dW = np_[(size_t)st * BATCH] * __builtin_sqrtf(dt);
        const float sd = s;

        float h, hacc;
        MLP_BODY(W1r, B1, W2r, B2, W3r, b3v, t, s, sd, h, hacc)
        const float hd = h * (1.0f - h) * hacc;

        const float mil = 0.5f * (dW * dW - dt);
        const float g1  = s * h;
        const float dg1 = fmaf(sd, h, s * hd);
        const float snew = s + s * dt + s * dW + sd * mil;
        pnl = pnl + g1 * dt + g1 * dW + dg1 * mil;
        s = snew;
    }

    const float z = fmaxf(0.0f, s - 3.0f);
    const float d = z - pnl - wv_;
    out[gid] = d * d;
}

extern "C" void kernel_launch(void* const* d_in, const int* in_sizes, int n_in,
                              void* d_out, int out_size, void* d_ws, size_t ws_size,
                              hipStream_t stream) {
    const float* noise = (const float*)d_in[0];
    const float* ts    = (const float*)d_in[1];
    const float* w     = (const float*)d_in[2];
    const float* W1    = (const float*)d_in[3];
    const float* b1    = (const float*)d_in[4];
    const float* W2    = (const float*)d_in[5];
    const float* b2    = (const float*)d_in[6];
    const float* W3    = (const float*)d_in[7];
    const float* b3    = (const float*)d_in[8];
    float* out = (float*)d_out;

    const size_t tblB = (size_t)NSTEPS * NPTS * sizeof(uint2);   // 256 KB
    const size_t pB   = (size_t)3 * BATCH * sizeof(float);       // 1.5 MB
    const size_t need = tblB + 2 * pB + (size_t)BATCH * sizeof(float);  // 3.75 MB

    if (ws_size >= need) {
        uint2* T2   = (uint2*)d_ws;
        float* P    = (float*)((char*)d_ws + tblB);
        float* pnlb = (float*)((char*)d_ws + tblB + pB);
        float* sT   = (float*)((char*)d_ws + tblB + 2 * pB);

        dim3 b(256);
        table_eval_kernel<<<dim3(NSTEPS * NPTS / 256), b, 0, stream>>>(
            ts, W1, b1, W2, b2, W3, b3, (unsigned int*)T2);
        prod_kernel<<<dim3(3 * BATCH / 256), b, 0, stream>>>(noise, ts, P);
        seg_kernel<<<dim3(4 * BATCH / 256), b, 0, stream>>>(
            noise, ts, T2, P, pnlb, sT, out);
        fin_kernel<<<dim3(BATCH / 256), b, 0, stream>>>(pnlb, sT, w, out);
    } else {
        dim3 grid(BATCH / 256), block(256);
        deep_hedging_direct<<<grid, block, 0, stream>>>(noise, ts, w, W1, b1,
                                                        W2, b2, W3, b3, out);
    }
}

// Round 20
// 70.238 us; speedup vs baseline: 1.0641x; 1.0342x over previous
//
#include <hip/hip_runtime.h>
#include <hip/hip_fp16.h>
#include <math.h>

#define BATCH 131072
#define NSTEPS 256
#define SEGLEN 128
#define LGN 7
#define NPTS 128           // (1 << LGN)
#define ZSPAN 12.0f        // z in [-6, 6]
#define ZLO 6.0f
#define ZSCALE (NPTS / ZSPAN)      // entries per sigma (10.667)
#define DZ (ZSPAN / NPTS)          // 0.09375
#define MU_C 0.72134752044448170367f   // (mu - sigma^2/2)/ln2 = 0.5/ln2
#define SD_C 1.4426950408889634f       // sigma/ln2

using f32x2 = __attribute__((ext_vector_type(2))) float;

__device__ __forceinline__ float fast_exp(float x) {
    return __builtin_amdgcn_exp2f(x * 1.44269504088896340736f);
}
__device__ __forceinline__ float fast_rcp(float x) {
    return __builtin_amdgcn_rcpf(x);
}
__device__ __forceinline__ float sigmoidf_fast(float x) {
    return fast_rcp(1.0f + fast_exp(-x));
}

#define REP32(M) M(0) M(1) M(2) M(3) M(4) M(5) M(6) M(7) \
                 M(8) M(9) M(10) M(11) M(12) M(13) M(14) M(15) \
                 M(16) M(17) M(18) M(19) M(20) M(21) M(22) M(23) \
                 M(24) M(25) M(26) M(27) M(28) M(29) M(30) M(31)

#define REP8(M) M(0) M(1) M(2) M(3) M(4) M(5) M(6) M(7)

// Shared MLP+tangent body (see R4). Produces h and pre-sigmoid tangent acc.
#define MLP_BODY(W1r, B1, W2r, B2, W3r, b3v, t, s, sd, H, HACC) \
    { \
        const float __t = (t), __s = (s), __sd = (sd); \
        f32x2 acc2 = {(b3v), 0.0f}; \
        REP32(MLP_L1) \
        REP32(MLP_ROW) \
        H = sigmoidf_fast(acc2.x); \
        HACC = acc2.y; \
    }

#define MLP_L1(j) f32x2 at##j; { \
    const float2 wv = W1r[j]; \
    const float z  = fmaf(wv.x, __t, fmaf(wv.y, __s, B1[j])); \
    const float zd = wv.y * __sd; \
    const float sg = sigmoidf_fast(z); \
    const float da = sg * (1.0f + z * (1.0f - sg)); \
    at##j = (f32x2){z * sg, da * zd}; }

#define MLP_ROW(j) { \
    const float4 q0 = W2r[(j) * 8 + 0]; \
    const float4 q1 = W2r[(j) * 8 + 1]; \
    const float4 q2 = W2r[(j) * 8 + 2]; \
    const float4 q3 = W2r[(j) * 8 + 3]; \
    const float4 q4 = W2r[(j) * 8 + 4]; \
    const float4 q5 = W2r[(j) * 8 + 5]; \
    const float4 q6 = W2r[(j) * 8 + 6]; \
    const float4 q7 = W2r[(j) * 8 + 7]; \
    f32x2 zza = {B2[j], 0.0f}; \
    f32x2 zzb = {0.0f, 0.0f}; \
    zza += (f32x2){q0.x, q0.x} * at0;  zzb += (f32x2){q0.y, q0.y} * at1; \
    zza += (f32x2){q0.z, q0.z} * at2;  zzb += (f32x2){q0.w, q0.w} * at3; \
    zza += (f32x2){q1.x, q1.x} * at4;  zzb += (f32x2){q1.y, q1.y} * at5; \
    zza += (f32x2){q1.z, q1.z} * at6;  zzb += (f32x2){q1.w, q1.w} * at7; \
    zza += (f32x2){q2.x, q2.x} * at8;  zzb += (f32x2){q2.y, q2.y} * at9; \
    zza += (f32x2){q2.z, q2.z} * at10; zzb += (f32x2){q2.w, q2.w} * at11; \
    zza += (f32x2){q3.x, q3.x} * at12; zzb += (f32x2){q3.y, q3.y} * at13; \
    zza += (f32x2){q3.z, q3.z} * at14; zzb += (f32x2){q3.w, q3.w} * at15; \
    zza += (f32x2){q4.x, q4.x} * at16; zzb += (f32x2){q4.y, q4.y} * at17; \
    zza += (f32x2){q4.z, q4.z} * at18; zzb += (f32x2){q4.w, q4.w} * at19; \
    zza += (f32x2){q5.x, q5.x} * at20; zzb += (f32x2){q5.y, q5.y} * at21; \
    zza += (f32x2){q5.z, q5.z} * at22; zzb += (f32x2){q5.w, q5.w} * at23; \
    zza += (f32x2){q6.x, q6.x} * at24; zzb += (f32x2){q6.y, q6.y} * at25; \
    zza += (f32x2){q6.z, q6.z} * at26; zzb += (f32x2){q6.w, q6.w} * at27; \
    zza += (f32x2){q7.x, q7.x} * at28; zzb += (f32x2){q7.y, q7.y} * at29; \
    zza += (f32x2){q7.z, q7.z} * at30; zzb += (f32x2){q7.w, q7.w} * at31; \
    const f32x2 zzt = zza + zzb; \
    const float zv  = zzt.x; \
    const float sg  = sigmoidf_fast(zv); \
    const float da  = sg * (1.0f + zv * (1.0f - sg)); \
    const float w3  = W3r[j]; \
    acc2 += (f32x2){w3, w3} * (f32x2){zv * sg, da * zzt.y}; \
}

// ---------------------------------------------------------------------------
// Kernel 1: table of packed half2{h, q} at standardized grid points, paired.
// ---------------------------------------------------------------------------
__global__ __launch_bounds__(256) void table_eval_kernel(
    const float* __restrict__ ts,
    const float* __restrict__ W1, const float* __restrict__ b1,
    const float* __restrict__ W2, const float* __restrict__ b2,
    const float* __restrict__ W3, const float* __restrict__ b3,
    unsigned int* __restrict__ W)      // = (unsigned int*)T2, 2 words/entry
{
    __shared__ __align__(16) float sW1[64];
    __shared__ float sb1[32];
    __shared__ __align__(16) float sW2[1024];
    __shared__ float sb2[32];
    __shared__ float sW3[32];
    __shared__ float sb3[1];

    const int tid = threadIdx.x;
    for (int i = tid; i < 1024; i += 256) sW2[i] = W2[i];
    if (tid < 64) sW1[tid] = W1[tid];
    if (tid < 32) { sb1[tid] = b1[tid]; sb2[tid] = b2[tid]; sW3[tid] = W3[tid]; }
    if (tid == 0) sb3[0] = b3[0];
    __syncthreads();

    const float2* W1r = (const float2*)sW1;
    const float*  B1  = sb1;
    const float4* W2r = (const float4*)sW2;
    const float*  B2  = sb2;
    const float*  W3r = sW3;
    const float   b3v = sb3[0];

    const int gid = blockIdx.x * 256 + tid;
    const int st = gid >> LGN;
    const int k  = gid & (NPTS - 1);

    const float t  = ts[st];
    const float mu = MU_C * t;
    const float sd = SD_C * __builtin_sqrtf(t) + 1e-4f;
    const float zz = fmaf((float)k, DZ, -ZLO);
    const float s  = __builtin_amdgcn_exp2f(fmaf(zz, sd, mu));

    float h, hacc;
    MLP_BODY(W1r, B1, W2r, B2, W3r, b3v, t, s, 1.0f, h, hacc)

    const float q = h * (1.0f - h) * hacc * s;   // s * dh/ds (Hermite tangent)
    __half2 p = __floats2half2_rn(h, q);
    const unsigned int pv = *(unsigned int*)&p;

    W[2 * gid] = pv;                       // T2[st][k].x
    if (k > 0)         W[2 * gid - 1] = pv;  // T2[st][k-1].y
    if (k == NPTS - 1) W[2 * gid + 1] = pv;  // row-end clamp
}

// ---------------------------------------------------------------------------
// Kernel 2: fused 2-segment path integration.  2*BATCH threads -> 4096 waves
// -> 4 waves/SIMD (2x the TLP; R14-R18 showed the residual is latency
// exposure at 2 waves/SIMD).  g = blockIdx.x & 1 so g=0 and g=1 blocks of
// neighboring paths share a CU (g=1's pre-chain reads the same noise rows
// g=0's full pass reads -> L2-hot).
//   g=0: full table pass on steps 0..127, pnl -> out (scratch).
//   g=1: cheap s-chain (no table, ~10 VALU/step) over steps 0..127 to get
//        the segment-boundary s, then full table pass on steps 128..255;
//        writes pnl1 and s_T.  No extra kernel, no P round-trip (R19's
//        mistake).
// ---------------------------------------------------------------------------
__global__ __launch_bounds__(256, 4) void path2_kernel(
    const float* __restrict__ noise,   // (NSTEPS, BATCH)
    const float* __restrict__ ts,      // (NSTEPS+1)
    const uint2* __restrict__ T2,      // (NSTEPS, NPTS)
    float* __restrict__ out,           // (BATCH)  g=0 pnl scratch
    float* __restrict__ pnlb,          // (BATCH)  g=1 pnl
    float* __restrict__ sT)            // (BATCH)  terminal s
{
    __shared__ float4 sdt4[SEGLEN];    // this segment: {dt, sqrt(dt), c', w'}
    __shared__ float  scr[SEGLEN];     // cr = ln2 / w'
    __shared__ float2 spre[SEGLEN];    // pre-chain rows 0..127: {dt, sqrt(dt)}

    const int g    = blockIdx.x & 1;
    const int pblk = blockIdx.x >> 1;
    const int tid  = threadIdx.x;
    const int sbase = g * SEGLEN;

    if (tid < SEGLEN) {
        const float t0  = ts[sbase + tid];
        const float dtv = ts[sbase + tid + 1] - t0;
        const float sdv = SD_C * __builtin_sqrtf(t0) + 1e-4f;
        const float wp  = fast_rcp(sdv) * ZSCALE;
        const float cp  = ZLO * ZSCALE - MU_C * t0 * wp;
        sdt4[tid] = make_float4(dtv, __builtin_sqrtf(dtv), cp, wp);
        scr[tid]  = 0.69314718056f * fast_rcp(wp);
    } else {
        const int r = tid - SEGLEN;    // rows 0..127 for the pre-chain
        const float t0  = ts[r];
        const float dtv = ts[r + 1] - t0;
        spre[r] = make_float2(dtv, __builtin_sqrtf(dtv));
    }
    __syncthreads();

    const int path = pblk * 256 + tid;
    const float umax = (float)NPTS - 1.001f;

    float s = 1.0f;
    if (g) {
        // cheap s-chain over steps 0..127 (noise rows L2-hot: the paired
        // g=0 block on this CU reads the same rows for its full pass)
        const float* npp = noise + path;
        #pragma unroll 1
        for (int c = 0; c < SEGLEN / 8; ++c) {
            const int b0 = c * 8;
            #define PLD(k) const float a##k = npp[(size_t)(b0 + k) * BATCH];
            REP8(PLD)
            #undef PLD
            #define PCH(k) { \
                const float2 d = spre[b0 + k]; \
                const float dW  = a##k * d.y; \
                const float mil = 0.5f * fmaf(dW, dW, -d.x); \
                const float A   = d.x + dW + mil; \
                s = fmaf(s, A, s); }
            REP8(PCH)
            #undef PCH
        }
    }

    const float* np_ = noise + (size_t)sbase * BATCH + path;
    float pnl = 0.0f;

    // preload chunk 0 noise
    #define NLD0(k) float n##k = np_[(size_t)(k) * BATCH];
    REP8(NLD0)
    #undef NLD0

    #pragma unroll 1
    for (int cc = 0; cc < SEGLEN / 8; ++cc) {
        const int coff = cc * 8;
        const int pfo  = min(coff + 8, SEGLEN - 8);
        const float* nb = np_ + (size_t)pfo * BATCH;

        // prefetch next chunk's noise
        #define NPF(k) const float m##k = nb[(size_t)(k) * BATCH];
        REP8(NPF)
        #undef NPF

        // s-chain + issue 8 paired gathers
        #define CHK(k) \
            const float4 dq##k = sdt4[coff + k]; \
            const float dW##k  = n##k * dq##k.y; \
            const float mil##k = 0.5f * fmaf(dW##k, dW##k, -dq##k.x); \
            const float Af##k  = dq##k.x + dW##k + mil##k; \
            const float sv##k  = s; \
            s = fmaf(s, Af##k, s); \
            const float Pv##k = sv##k * Af##k; \
            const float Qv##k = sv##k * mil##k; \
            const float x##k = __builtin_amdgcn_logf(sv##k); \
            const float u##k = \
                fminf(fmaxf(fmaf(x##k, dq##k.w, dq##k.z), 0.0f), umax); \
            const int   i0##k = (int)u##k; \
            const float f##k  = u##k - (float)i0##k; \
            const uint2 E##k = \
                T2[((size_t)(sbase + coff + k) << LGN) + i0##k];
        REP8(CHK)
        #undef CHK

        // consume: cubic Hermite h, linear q; pnl += hh*Pv + qq*Qv
        #define PNK(k) { \
            const float2 a0 = __half22float2(*(const __half2*)&E##k.x); \
            const float2 a1 = __half22float2(*(const __half2*)&E##k.y); \
            const float cr = scr[coff + k]; \
            const float uu = f##k; \
            const float m  = uu * uu; \
            const float n  = m * uu; \
            const float dh = a1.x - a0.x; \
            const float ba = fmaf(-2.0f, n, 3.0f * m); \
            const float bb = fmaf(-2.0f, m, uu) + n; \
            const float bc = n - m; \
            const float hh = fmaf(dh, ba, a0.x) + cr * fmaf(a0.y, bb, a1.y * bc); \
            const float qq = fmaf(uu, a1.y - a0.y, a0.y); \
            pnl = fmaf(hh, Pv##k, fmaf(qq, Qv##k, pnl)); }
        REP8(PNK)
        #undef PNK

        // rotate prefetched noise
        #define NRT(k) n##k = m##k;
        REP8(NRT)
        #undef NRT
    }

    if (g == 0) {
        out[path] = pnl;               // scratch; fin_kernel combines
    } else {
        pnlb[path] = pnl;
        sT[path] = s;
    }
}

// ---------------------------------------------------------------------------
// Kernel 3: combine.
// ---------------------------------------------------------------------------
__global__ __launch_bounds__(256) void fin_kernel(
    const float* __restrict__ pnlb, const float* __restrict__ sT,
    const float* __restrict__ wq, float* __restrict__ out)
{
    const int p = blockIdx.x * 256 + threadIdx.x;
    const float pnl = out[p] + pnlb[p];
    const float z = fmaxf(0.0f, sT[p] - 3.0f);
    const float d = z - pnl - wq[0];
    out[p] = d * d;
}

// ---------------------------------------------------------------------------
// Fallback: direct per-thread MLP evaluation (R4 kernel) if ws too small.
// ---------------------------------------------------------------------------
__global__ __launch_bounds__(256, 3) void deep_hedging_direct(
    const float* __restrict__ noise, const float* __restrict__ ts,
    const float* __restrict__ w,
    const float* __restrict__ W1, const float* __restrict__ b1,
    const float* __restrict__ W2, const float* __restrict__ b2,
    const float* __restrict__ W3, const float* __restrict__ b3,
    float* __restrict__ out)
{
    __shared__ __align__(16) float sW1[64];
    __shared__ float sb1[32];
    __shared__ __align__(16) float sW2[1024];
    __shared__ float sb2[32];
    __shared__ float sW3[32];
    __shared__ float sb3w[2];
    __shared__ float sts[NSTEPS + 1];

    const int tid = threadIdx.x;
    for (int i = tid; i < 1024; i += 256) sW2[i] = W2[i];
    if (tid < 64) sW1[tid] = W1[tid];
    if (tid < 32) { sb1[tid] = b1[tid]; sb2[tid] = b2[tid]; sW3[tid] = W3[tid]; }
    if (tid == 0) { sb3w[0] = b3[0]; sb3w[1] = w[0]; }
    for (int i = tid; i < NSTEPS + 1; i += 256) sts[i] = ts[i];
    __syncthreads();

    const int gid = blockIdx.x * 256 + tid;
    const float* np_ = noise + gid;

    float s   = 1.0f;
    float pnl = 0.0f;
    const float b3v = sb3w[0];
    const float wv_ = sb3w[1];

    #pragma unroll 1
    for (int st = 0; st < NSTEPS; ++st) {
        int zr = 0;
        asm volatile("" : "+v"(zr));   // block LICM of weight loads
        const float2* W1r = (const float2*)sW1 + zr;
        const float*  B1  = sb1 + zr;
        const float4* W2r = (const float4*)sW2 + zr;
        const float*  B2  = sb2 + zr;
        const float*  W3r = sW3 + zr;

        const float t  = sts[st];
        const float dt = sts[st + 1] - t;
        const float dW = np_[(size_t)st * BATCH] * __builtin_sqrtf(dt);
        const float sd = s;

        float h, hacc;
        MLP_BODY(W1r, B1, W2r, B2, W3r, b3v, t, s, sd, h, hacc)
        const float hd = h * (1.0f - h) * hacc;

        const float mil = 0.5f * (dW * dW - dt);
        const float g1  = s * h;
        const float dg1 = fmaf(sd, h, s * hd);
        const float snew = s + s * dt + s * dW + sd * mil;
        pnl = pnl + g1 * dt + g1 * dW + dg1 * mil;
        s = snew;
    }

    const float z = fmaxf(0.0f, s - 3.0f);
    const float d = z - pnl - wv_;
    out[gid] = d * d;
}

extern "C" void kernel_launch(void* const* d_in, const int* in_sizes, int n_in,
                              void* d_out, int out_size, void* d_ws, size_t ws_size,
                              hipStream_t stream) {
    const float* noise = (const float*)d_in[0];
    const float* ts    = (const float*)d_in[1];
    const float* w     = (const float*)d_in[2];
    const float* W1    = (const float*)d_in[3];
    const float* b1    = (const float*)d_in[4];
    const float* W2    = (const float*)d_in[5];
    const float* b2    = (const float*)d_in[6];
    const float* W3    = (const float*)d_in[7];
    const float* b3    = (const float*)d_in[8];
    float* out = (float*)d_out;

    const size_t tblB = (size_t)NSTEPS * NPTS * sizeof(uint2);     // 256 KB
    const size_t vecB = (size_t)BATCH * sizeof(float);             // 512 KB
    const size_t need = tblB + 2 * vecB;                           // 1.25 MB

    if (ws_size >= need) {
        uint2* T2   = (uint2*)d_ws;
        float* pnlb = (float*)((char*)d_ws + tblB);
        float* sT   = (float*)((char*)d_ws + tblB + vecB);

        dim3 b(256);
        table_eval_kernel<<<dim3(NSTEPS * NPTS / 256), b, 0, stream>>>(
            ts, W1, b1, W2, b2, W3, b3, (unsigned int*)T2);
        path2_kernel<<<dim3(2 * BATCH / 256), b, 0, stream>>>(
            noise, ts, T2, out, pnlb, sT);
        fin_kernel<<<dim3(BATCH / 256), b, 0, stream>>>(pnlb, sT, w, out);
    } else {
        dim3 grid(BATCH / 256), block(256);
        deep_hedging_direct<<<grid, block, 0, stream>>>(noise, ts, w, W1, b1,
                                                        W2, b2, W3, b3, out);
    }
}

// Round 21
// 62.328 us; speedup vs baseline: 1.1992x; 1.1269x over previous
//
#include <hip/hip_runtime.h>
#include <hip/hip_fp16.h>
#include <math.h>

#define BATCH 131072
#define NSTEPS 256
#define NPAIRS 128         // NSTEPS/2 table rows (even steps only)
#define LGN 7
#define NPTS 128           // (1 << LGN)
#define ZSPAN 12.0f        // z in [-6, 6]
#define ZLO 6.0f
#define ZSCALE (NPTS / ZSPAN)      // entries per sigma (10.667)
#define DZ (ZSPAN / NPTS)          // 0.09375
#define MU_C 0.72134752044448170367f   // (mu - sigma^2/2)/ln2 = 0.5/ln2
#define SD_C 1.4426950408889634f       // sigma/ln2

using f32x2 = __attribute__((ext_vector_type(2))) float;

__device__ __forceinline__ float fast_exp(float x) {
    return __builtin_amdgcn_exp2f(x * 1.44269504088896340736f);
}
__device__ __forceinline__ float fast_rcp(float x) {
    return __builtin_amdgcn_rcpf(x);
}
__device__ __forceinline__ float sigmoidf_fast(float x) {
    return fast_rcp(1.0f + fast_exp(-x));
}

#define REP32(M) M(0) M(1) M(2) M(3) M(4) M(5) M(6) M(7) \
                 M(8) M(9) M(10) M(11) M(12) M(13) M(14) M(15) \
                 M(16) M(17) M(18) M(19) M(20) M(21) M(22) M(23) \
                 M(24) M(25) M(26) M(27) M(28) M(29) M(30) M(31)

#define REP16(M) M(0) M(1) M(2) M(3) M(4) M(5) M(6) M(7) \
                 M(8) M(9) M(10) M(11) M(12) M(13) M(14) M(15)

// pairs in a 16-step chunk: M(pair, even-noise-reg, odd-noise-reg)
#define REPP(M) M(0,0,1) M(1,2,3) M(2,4,5) M(3,6,7) \
                M(4,8,9) M(5,10,11) M(6,12,13) M(7,14,15)

// Shared MLP+tangent body (see R4). Produces h and pre-sigmoid tangent acc.
#define MLP_BODY(W1r, B1, W2r, B2, W3r, b3v, t, s, sd, H, HACC) \
    { \
        const float __t = (t), __s = (s), __sd = (sd); \
        f32x2 acc2 = {(b3v), 0.0f}; \
        REP32(MLP_L1) \
        REP32(MLP_ROW) \
        H = sigmoidf_fast(acc2.x); \
        HACC = acc2.y; \
    }

#define MLP_L1(j) f32x2 at##j; { \
    const float2 wv = W1r[j]; \
    const float z  = fmaf(wv.x, __t, fmaf(wv.y, __s, B1[j])); \
    const float zd = wv.y * __sd; \
    const float sg = sigmoidf_fast(z); \
    const float da = sg * (1.0f + z * (1.0f - sg)); \
    at##j = (f32x2){z * sg, da * zd}; }

#define MLP_ROW(j) { \
    const float4 q0 = W2r[(j) * 8 + 0]; \
    const float4 q1 = W2r[(j) * 8 + 1]; \
    const float4 q2 = W2r[(j) * 8 + 2]; \
    const float4 q3 = W2r[(j) * 8 + 3]; \
    const float4 q4 = W2r[(j) * 8 + 4]; \
    const float4 q5 = W2r[(j) * 8 + 5]; \
    const float4 q6 = W2r[(j) * 8 + 6]; \
    const float4 q7 = W2r[(j) * 8 + 7]; \
    f32x2 zza = {B2[j], 0.0f}; \
    f32x2 zzb = {0.0f, 0.0f}; \
    zza += (f32x2){q0.x, q0.x} * at0;  zzb += (f32x2){q0.y, q0.y} * at1; \
    zza += (f32x2){q0.z, q0.z} * at2;  zzb += (f32x2){q0.w, q0.w} * at3; \
    zza += (f32x2){q1.x, q1.x} * at4;  zzb += (f32x2){q1.y, q1.y} * at5; \
    zza += (f32x2){q1.z, q1.z} * at6;  zzb += (f32x2){q1.w, q1.w} * at7; \
    zza += (f32x2){q2.x, q2.x} * at8;  zzb += (f32x2){q2.y, q2.y} * at9; \
    zza += (f32x2){q2.z, q2.z} * at10; zzb += (f32x2){q2.w, q2.w} * at11; \
    zza += (f32x2){q3.x, q3.x} * at12; zzb += (f32x2){q3.y, q3.y} * at13; \
    zza += (f32x2){q3.z, q3.z} * at14; zzb += (f32x2){q3.w, q3.w} * at15; \
    zza += (f32x2){q4.x, q4.x} * at16; zzb += (f32x2){q4.y, q4.y} * at17; \
    zza += (f32x2){q4.z, q4.z} * at18; zzb += (f32x2){q4.w, q4.w} * at19; \
    zza += (f32x2){q5.x, q5.x} * at20; zzb += (f32x2){q5.y, q5.y} * at21; \
    zza += (f32x2){q5.z, q5.z} * at22; zzb += (f32x2){q5.w, q5.w} * at23; \
    zza += (f32x2){q6.x, q6.x} * at24; zzb += (f32x2){q6.y, q6.y} * at25; \
    zza += (f32x2){q6.z, q6.z} * at26; zzb += (f32x2){q6.w, q6.w} * at27; \
    zza += (f32x2){q7.x, q7.x} * at28; zzb += (f32x2){q7.y, q7.y} * at29; \
    zza += (f32x2){q7.z, q7.z} * at30; zzb += (f32x2){q7.w, q7.w} * at31; \
    const f32x2 zzt = zza + zzb; \
    const float zv  = zzt.x; \
    const float sg  = sigmoidf_fast(zv); \
    const float da  = sg * (1.0f + zv * (1.0f - sg)); \
    const float w3  = W3r[j]; \
    acc2 += (f32x2){w3, w3} * (f32x2){zv * sg, da * zzt.y}; \
}

// ---------------------------------------------------------------------------
// Kernel 1: paired table over EVEN steps only: row p covers step 2p.
// T2[p][k] = {half2{h,q}(k), half2{h,q}(k+1)} at s = 2^(mu+(k*DZ-ZLO)*sd),
// t = ts[2p].  q = s*dh/ds (Hermite tangent AND the step-advance tangent).
// ---------------------------------------------------------------------------
__global__ __launch_bounds__(256) void table_eval_kernel(
    const float* __restrict__ ts,
    const float* __restrict__ W1, const float* __restrict__ b1,
    const float* __restrict__ W2, const float* __restrict__ b2,
    const float* __restrict__ W3, const float* __restrict__ b3,
    unsigned int* __restrict__ W)      // = (unsigned int*)T2, 2 words/entry
{
    __shared__ __align__(16) float sW1[64];
    __shared__ float sb1[32];
    __shared__ __align__(16) float sW2[1024];
    __shared__ float sb2[32];
    __shared__ float sW3[32];
    __shared__ float sb3[1];

    const int tid = threadIdx.x;
    for (int i = tid; i < 1024; i += 256) sW2[i] = W2[i];
    if (tid < 64) sW1[tid] = W1[tid];
    if (tid < 32) { sb1[tid] = b1[tid]; sb2[tid] = b2[tid]; sW3[tid] = W3[tid]; }
    if (tid == 0) sb3[0] = b3[0];
    __syncthreads();

    const float2* W1r = (const float2*)sW1;
    const float*  B1  = sb1;
    const float4* W2r = (const float4*)sW2;
    const float*  B2  = sb2;
    const float*  W3r = sW3;
    const float   b3v = sb3[0];

    const int gid = blockIdx.x * 256 + tid;
    const int p = gid >> LGN;          // pair index, 0..127
    const int k = gid & (NPTS - 1);

    const float t  = ts[2 * p];
    const float mu = MU_C * t;
    const float sd = SD_C * __builtin_sqrtf(t) + 1e-4f;
    const float zz = fmaf((float)k, DZ, -ZLO);
    const float s  = __builtin_amdgcn_exp2f(fmaf(zz, sd, mu));

    float h, hacc;
    MLP_BODY(W1r, B1, W2r, B2, W3r, b3v, t, s, 1.0f, h, hacc)

    const float q = h * (1.0f - h) * hacc * s;   // s * dh/ds
    __half2 pk = __floats2half2_rn(h, q);
    const unsigned int pv = *(unsigned int*)&pk;

    W[2 * gid] = pv;                       // T2[p][k].x
    if (k > 0)         W[2 * gid - 1] = pv;  // T2[p][k-1].y
    if (k == NPTS - 1) W[2 * gid + 1] = pv;  // row-end clamp
}

// ---------------------------------------------------------------------------
// Kernel 2: SDE path integration with STEP-PAIRING.  The s-chain runs every
// step (exact -> s_T and the strike kink unchanged), but the table lookup
// (log2 + index + gather + Hermite, ~20 ops) runs once per PAIR; the odd
// step advances h along its own stored tangent: ds/s = A0 exactly, so
// h1 = h0 + q0*A0, q1 ~ q0 (only multiplies the tiny mil term).  Halves
// both the per-step VALU and the gather count.
// ---------------------------------------------------------------------------
__global__ __launch_bounds__(256, 2) void path_kernel(
    const float* __restrict__ noise,   // (NSTEPS, BATCH)
    const float* __restrict__ ts,      // (NSTEPS+1)
    const float* __restrict__ wq,      // scalar
    const uint2* __restrict__ T2,      // (NPAIRS, NPTS)
    float* __restrict__ out)           // (BATCH)
{
    __shared__ float4 sPc[NPAIRS];     // {dt0, sqrt(dt0), dt1, sqrt(dt1)}
    __shared__ float4 sQc[NPAIRS];     // {c', w', cr, 0} at t_{2p}
    const int tid = threadIdx.x;
    if (tid < NPAIRS) {
        const int p = tid;
        const float t0  = ts[2 * p];
        const float dt0 = ts[2 * p + 1] - t0;
        const float dt1 = ts[2 * p + 2] - ts[2 * p + 1];
        sPc[p] = make_float4(dt0, __builtin_sqrtf(dt0),
                             dt1, __builtin_sqrtf(dt1));
        const float sdv = SD_C * __builtin_sqrtf(t0) + 1e-4f;
        const float wp  = fast_rcp(sdv) * ZSCALE;
        const float cp  = ZLO * ZSCALE - MU_C * t0 * wp;
        sQc[p] = make_float4(cp, wp, 0.69314718056f * fast_rcp(wp), 0.0f);
    }
    __syncthreads();

    const int gid = blockIdx.x * 256 + tid;
    const float* np_ = noise + gid;
    const float umax = (float)NPTS - 1.001f;

    float s   = 1.0f;
    float pnl = 0.0f;

    // preload chunk 0 noise (16 steps = 8 pairs)
    #define NLD0(k) float nn##k = np_[(size_t)(k) * BATCH];
    REP16(NLD0)
    #undef NLD0

    #pragma unroll 1
    for (int cc = 0; cc < NPAIRS / 8; ++cc) {
        const int cbase = cc * 8;              // pair offset
        const int pfo   = min((cc + 1) * 16, NSTEPS - 16);
        const float* nb = np_ + (size_t)pfo * BATCH;

        // prefetch next chunk's noise
        #define NPF(k) const float mm##k = nb[(size_t)(k) * BATCH];
        REP16(NPF)
        #undef NPF

        // per pair: 2-step s-chain + one gather
        #define CHP(p, e, o) \
            const float4 pc##p = sPc[cbase + p]; \
            const float4 qc##p = sQc[cbase + p]; \
            const float dW0##p  = nn##e * pc##p.y; \
            const float mil0##p = 0.5f * fmaf(dW0##p, dW0##p, -pc##p.x); \
            const float A0##p   = pc##p.x + dW0##p + mil0##p; \
            const float sv0##p  = s; \
            s = fmaf(s, A0##p, s); \
            const float dW1##p  = nn##o * pc##p.w; \
            const float mil1##p = 0.5f * fmaf(dW1##p, dW1##p, -pc##p.z); \
            const float A1##p   = pc##p.z + dW1##p + mil1##p; \
            const float sv1##p  = s; \
            s = fmaf(s, A1##p, s); \
            const float x##p = __builtin_amdgcn_logf(sv0##p); \
            const float u##p = \
                fminf(fmaxf(fmaf(x##p, qc##p.y, qc##p.x), 0.0f), umax); \
            const int   i0##p = (int)u##p; \
            const float f##p  = u##p - (float)i0##p; \
            const uint2 E##p = \
                T2[((size_t)(cbase + p) << LGN) + i0##p];
        REPP(CHP)
        #undef CHP

        // consume: Hermite h0, linear q0; odd step via tangent advance
        #define PNP(p, e, o) { \
            const float2 a0 = __half22float2(*(const __half2*)&E##p.x); \
            const float2 a1 = __half22float2(*(const __half2*)&E##p.y); \
            const float uu = f##p; \
            const float m  = uu * uu; \
            const float n  = m * uu; \
            const float dh = a1.x - a0.x; \
            const float ba = fmaf(-2.0f, n, 3.0f * m); \
            const float bb = fmaf(-2.0f, m, uu) + n; \
            const float bc = n - m; \
            const float h0 = fmaf(dh, ba, a0.x) \
                           + qc##p.z * fmaf(a0.y, bb, a1.y * bc); \
            const float q0 = fmaf(uu, a1.y - a0.y, a0.y); \
            pnl = fmaf(sv0##p, fmaf(h0, A0##p, q0 * mil0##p), pnl); \
            const float h1 = fmaf(q0, A0##p, h0); \
            pnl = fmaf(sv1##p, fmaf(h1, A1##p, q0 * mil1##p), pnl); }
        REPP(PNP)
        #undef PNP

        // rotate prefetched noise
        #define NRT(k) nn##k = mm##k;
        REP16(NRT)
        #undef NRT
    }

    const float z = fmaxf(0.0f, s - 3.0f);
    const float d = z - pnl - wq[0];
    out[gid] = d * d;
}

// ---------------------------------------------------------------------------
// Fallback: direct per-thread MLP evaluation (R4 kernel) if ws too small.
// ---------------------------------------------------------------------------
__global__ __launch_bounds__(256, 3) void deep_hedging_direct(
    const float* __restrict__ noise, const float* __restrict__ ts,
    const float* __restrict__ w,
    const float* __restrict__ W1, const float* __restrict__ b1,
    const float* __restrict__ W2, const float* __restrict__ b2,
    const float* __restrict__ W3, const float* __restrict__ b3,
    float* __restrict__ out)
{
    __shared__ __align__(16) float sW1[64];
    __shared__ float sb1[32];
    __shared__ __align__(16) float sW2[1024];
    __shared__ float sb2[32];
    __shared__ float sW3[32];
    __shared__ float sb3w[2];
    __shared__ float sts[NSTEPS + 1];

    const int tid = threadIdx.x;
    for (int i = tid; i < 1024; i += 256) sW2[i] = W2[i];
    if (tid < 64) sW1[tid] = W1[tid];
    if (tid < 32) { sb1[tid] = b1[tid]; sb2[tid] = b2[tid]; sW3[tid] = W3[tid]; }
    if (tid == 0) { sb3w[0] = b3[0]; sb3w[1] = w[0]; }
    for (int i = tid; i < NSTEPS + 1; i += 256) sts[i] = ts[i];
    __syncthreads();

    const int gid = blockIdx.x * 256 + tid;
    const float* np_ = noise + gid;

    float s   = 1.0f;
    float pnl = 0.0f;
    const float b3v = sb3w[0];
    const float wv_ = sb3w[1];

    #pragma unroll 1
    for (int st = 0; st < NSTEPS; ++st) {
        int zr = 0;
        asm volatile("" : "+v"(zr));   // block LICM of weight loads
        const float2* W1r = (const float2*)sW1 + zr;
        const float*  B1  = sb1 + zr;
        const float4* W2r = (const float4*)sW2 + zr;
        const float*  B2  = sb2 + zr;
        const float*  W3r = sW3 + zr;

        const float t  = sts[st];
        const float dt = sts[st + 1] - t;
        const float dW = np_[(size_t)st * BATCH] * __builtin_sqrtf(dt);
        const float sd = s;

        float h, hacc;
        MLP_BODY(W1r, B1, W2r, B2, W3r, b3v, t, s, sd, h, hacc)
        const float hd = h * (1.0f - h) * hacc;

        const float mil = 0.5f * (dW * dW - dt);
        const float g1  = s * h;
        const float dg1 = fmaf(sd, h, s * hd);
        const float snew = s + s * dt + s * dW + sd * mil;
        pnl = pnl + g1 * dt + g1 * dW + dg1 * mil;
        s = snew;
    }

    const float z = fmaxf(0.0f, s - 3.0f);
    const float d = z - pnl - wv_;
    out[gid] = d * d;
}

extern "C" void kernel_launch(void* const* d_in, const int* in_sizes, int n_in,
                              void* d_out, int out_size, void* d_ws, size_t ws_size,
                              hipStream_t stream) {
    const float* noise = (const float*)d_in[0];
    const float* ts    = (const float*)d_in[1];
    const float* w     = (const float*)d_in[2];
    const float* W1    = (const float*)d_in[3];
    const float* b1    = (const float*)d_in[4];
    const float* W2    = (const float*)d_in[5];
    const float* b2    = (const float*)d_in[6];
    const float* W3    = (const float*)d_in[7];
    const float* b3    = (const float*)d_in[8];
    float* out = (float*)d_out;

    const size_t nA   = (size_t)NPAIRS * NPTS;           // entries
    const size_t need = nA * sizeof(uint2);              // 128 KB

    if (ws_size >= need) {
        uint2* T2 = (uint2*)d_ws;

        dim3 b(256);
        table_eval_kernel<<<dim3(nA / 256), b, 0, stream>>>(
            ts, W1, b1, W2, b2, W3, b3, (unsigned int*)T2);
        path_kernel<<<dim3(BATCH / 256), b, 0, stream>>>(
            noise, ts, w, T2, out);
    } else {
        dim3 grid(BATCH / 256), block(256);
        deep_hedging_direct<<<grid, block, 0, stream>>>(noise, ts, w, W1, b1,
                                                        W2, b2, W3, b3, out);
    }
}